// Round 4
// baseline (439.725 us; speedup 1.0000x reference)
//
#include <hip/hip_runtime.h>
#include <hip/hip_bf16.h>

#define B_ 256
#define D_ 2048
#define N_ 30000
#define INV_TEMP 20.0f
#define MOM 0.2f
#define EPSF 1e-12f
#define BN 48
#define KC 64
#define NT 625   // 30000 / 48
#define NK 32    // D_ / KC

typedef __attribute__((ext_vector_type(8))) short bf16x8;
typedef __attribute__((ext_vector_type(4))) float f32x4;

__device__ __forceinline__ unsigned short f2bf(float f) {
  union { float f; unsigned int u; } v; v.f = f;
  unsigned int u = v.u;
  unsigned int r = (u + 0x7fffu + ((u >> 16) & 1u)) >> 16;
  return (unsigned short)r;
}

__device__ __forceinline__ bf16x8 pack8(float4 a, float4 b) {
  bf16x8 r;
  r[0] = (short)f2bf(a.x); r[1] = (short)f2bf(a.y);
  r[2] = (short)f2bf(a.z); r[3] = (short)f2bf(a.w);
  r[4] = (short)f2bf(b.x); r[5] = (short)f2bf(b.y);
  r[6] = (short)f2bf(b.z); r[7] = (short)f2bf(b.w);
  return r;
}

__device__ __forceinline__ float blockReduceSum256(float v) {
  __shared__ float red[4];
  #pragma unroll
  for (int m = 32; m >= 1; m >>= 1) v += __shfl_xor(v, m, 64);
  int lane = threadIdx.x & 63, w = threadIdx.x >> 6;
  __syncthreads();
  if (lane == 0) red[w] = v;
  __syncthreads();
  return red[0] + red[1] + red[2] + red[3];
}

// ---------------- Kernel A: normalize inputs, emit fp32 + bf16 copies -------
__global__ __launch_bounds__(256) void knorm(const float* __restrict__ in,
                                             float* __restrict__ x,
                                             unsigned short* __restrict__ xbf) {
  int b = blockIdx.x, t = threadIdx.x;
  const float* row = in + (size_t)b * D_;
  float vals[8]; float ss = 0.f;
  #pragma unroll
  for (int i = 0; i < 8; i++) { float f = row[t + i * 256]; vals[i] = f; ss += f * f; }
  float tot = blockReduceSum256(ss);
  float inv = 1.0f / (sqrtf(tot) + EPSF);
  #pragma unroll
  for (int i = 0; i < 8; i++) {
    float xv = vals[i] * inv;
    x[(size_t)b * D_ + t + i * 256] = xv;
    xbf[(size_t)b * D_ + t + i * 256] = f2bf(xv);
  }
}

// ---------------- Kernel B: barrier-free fragment-direct GEMM + copy --------
// 6 waves = 2(M) x 3(N). Wave (mh,nw): batch rows [mh*128, mh*128+128),
// feature cols [n0+nw*16, +16). A-frags direct from xbf (L2-hot);
// B-frags direct from fp32 feats (HBM stream) with in-reg bf16 pack and
// shuffle-realigned aligned-float4 copy to out+1. No K-loop barriers.
__global__ __launch_bounds__(384, 3) void kmain(const float* __restrict__ feats,
                                                const unsigned short* __restrict__ xbf,
                                                float* __restrict__ outp,
                                                float* __restrict__ pmax,
                                                float* __restrict__ psum) {
  __shared__ float pm[3][256], ps[3][256];
  int tid = threadIdx.x, wave = tid >> 6, lane = tid & 63;
  int mh = wave / 3, nw = wave % 3;
  int q = lane >> 4, lr = lane & 15;
  int n0 = blockIdx.x * BN;
  int nrow = n0 + nw * 16 + lr;                 // feats row for B-frag/copy
  const float* fbase = feats + (size_t)nrow * D_;
  int sl = (lane + 16) & 63;                     // next quad (wrap; unused at q==3)

  f32x4 acc[8];
  #pragma unroll
  for (int i = 0; i < 8; i++) acc[i] = f32x4{0.f, 0.f, 0.f, 0.f};

  float4 fv[2][2];   // [ks][lo/hi] fp32 B staging for tile t (prefetched)
  // prologue: load tile 0
  #pragma unroll
  for (int ks = 0; ks < 2; ks++) {
    fv[ks][0] = *(const float4*)(fbase + ks * 32 + q * 8);
    fv[ks][1] = *(const float4*)(fbase + ks * 32 + q * 8 + 4);
  }

  for (int t = 0; t < NK; t++) {
    // convert current tile's B to bf16 frags
    bf16x8 bcur[2];
    #pragma unroll
    for (int ks = 0; ks < 2; ks++) bcur[ks] = pack8(fv[ks][0], fv[ks][1]);

    // fused copy feats -> out+1, realigned to 16B-aligned float4 stores
    if (mh == 0) {
      #pragma unroll
      for (int ks = 0; ks < 2; ks++) {
        int K = t * KC + ks * 32;
        float4 A = fv[ks][0], Bv = fv[ks][1];
        float nx = __shfl(A.x, sl, 64);
        float ny = __shfl(A.y, sl, 64);
        float nz = __shfl(A.z, sl, 64);
        size_t rb = (size_t)nrow * D_ + K;       // out-absolute base (out+1 shift folded)
        *(float4*)(outp + rb + 4 * (2 * q + 1)) = make_float4(A.w, Bv.x, Bv.y, Bv.z);
        if (q < 3) *(float4*)(outp + rb + 4 * (2 * q + 2)) = make_float4(Bv.w, nx, ny, nz);
        if (q == 0) { outp[rb + 1] = A.x; outp[rb + 2] = A.y; outp[rb + 3] = A.z; }
        if (q == 3) outp[rb + 32] = Bv.w;
      }
    }

    // prefetch next tile's B (HBM; rides over the MFMA block + next stores)
    int tn = (t + 1 < NK) ? t + 1 : t;
    #pragma unroll
    for (int ks = 0; ks < 2; ks++) {
      fv[ks][0] = *(const float4*)(fbase + tn * KC + ks * 32 + q * 8);
      fv[ks][1] = *(const float4*)(fbase + tn * KC + ks * 32 + q * 8 + 4);
    }

    // A-frags from global (L2-hot) + MFMA
    #pragma unroll
    for (int ks = 0; ks < 2; ks++) {
      bf16x8 a[8];
      size_t ab = (size_t)(mh * 128 + lr) * D_ + t * KC + ks * 32 + q * 8;
      #pragma unroll
      for (int mi = 0; mi < 8; mi++)
        a[mi] = *(const bf16x8*)(xbf + ab + (size_t)mi * 16 * D_);
      #pragma unroll
      for (int mi = 0; mi < 8; mi++)
        acc[mi] = __builtin_amdgcn_mfma_f32_16x16x32_bf16(a[mi], bcur[ks], acc[mi], 0, 0, 0);
    }
  }

  // epilogue: per-wave 16-col partials, LDS-combine across the 3 N-waves
  #pragma unroll
  for (int mi = 0; mi < 8; mi++) {
    #pragma unroll
    for (int r = 0; r < 4; r++) {
      float v = acc[mi][r] * INV_TEMP;
      float mx = v;
      #pragma unroll
      for (int m = 8; m >= 1; m >>= 1) mx = fmaxf(mx, __shfl_xor(mx, m, 64));
      float s = __expf(v - mx);
      #pragma unroll
      for (int m = 8; m >= 1; m >>= 1) s += __shfl_xor(s, m, 64);
      if (lr == 0) {
        int row = mh * 128 + mi * 16 + q * 4 + r;
        pm[nw][row] = mx; ps[nw][row] = s;
      }
    }
  }
  __syncthreads();
  if (tid < 256) {
    float m0 = pm[0][tid], m1 = pm[1][tid], m2 = pm[2][tid];
    float M = fmaxf(fmaxf(m0, m1), m2);
    float S = ps[0][tid] * __expf(m0 - M) + ps[1][tid] * __expf(m1 - M) +
              ps[2][tid] * __expf(m2 - M);
    pmax[(size_t)tid * NT + blockIdx.x] = M;
    psum[(size_t)tid * NT + blockIdx.x] = S;
  }
}

// ---------------- Kernel C: exact fp32 target logits ------------------------
__global__ __launch_bounds__(256) void ktdot(const float* __restrict__ feats,
                                             const float* __restrict__ x,
                                             const int* __restrict__ tgt,
                                             float* __restrict__ tdot) {
  int b = blockIdx.x, t = threadIdx.x;
  int y = tgt[b];
  const float* fr = feats + (size_t)y * D_;
  const float* xr = x + (size_t)b * D_;
  float s = 0.f;
  #pragma unroll
  for (int i = 0; i < 8; i++) s += fr[t + i * 256] * xr[t + i * 256];
  float tot = blockReduceSum256(s);
  if (t == 0) tdot[b] = tot * INV_TEMP;
}

// ---------------- Kernel D1: per-row logsumexp combine (256 blocks) ---------
__global__ __launch_bounds__(256) void kloss1(const float* __restrict__ pmax,
                                              const float* __restrict__ psum,
                                              const float* __restrict__ tdot,
                                              float* __restrict__ lb) {
  int b = blockIdx.x, t = threadIdx.x;
  float m = -INFINITY, s = 0.f;
  for (int i = t; i < NT; i += 256) {
    float mt = pmax[(size_t)b * NT + i];
    float st = psum[(size_t)b * NT + i];
    if (mt > m) { s = s * __expf(m - mt) + st; m = mt; }
    else        { s += st * __expf(mt - m); }
  }
  #pragma unroll
  for (int w = 32; w >= 1; w >>= 1) {
    float mo = __shfl_xor(m, w, 64);
    float so = __shfl_xor(s, w, 64);
    float M = fmaxf(m, mo);
    s = s * __expf(m - M) + so * __expf(mo - M);
    m = M;
  }
  __shared__ float sm[4], ssum[4];
  int lane = t & 63, w = t >> 6;
  if (lane == 0) { sm[w] = m; ssum[w] = s; }
  __syncthreads();
  if (t == 0) {
    float M = fmaxf(fmaxf(sm[0], sm[1]), fmaxf(sm[2], sm[3]));
    float S = ssum[0] * __expf(sm[0] - M) + ssum[1] * __expf(sm[1] - M) +
              ssum[2] * __expf(sm[2] - M) + ssum[3] * __expf(sm[3] - M);
    lb[b] = M + logf(S) - tdot[b];
  }
}

// ---------------- Kernel D2: mean over batch -> loss ------------------------
__global__ __launch_bounds__(256) void kloss2(const float* __restrict__ lb,
                                              float* __restrict__ out) {
  int t = threadIdx.x;
  float tot = blockReduceSum256(lb[t]);
  if (t == 0) out[0] = tot * (1.0f / 256.0f);
}

// ---------------- Kernel E: momentum update (first-occurrence chains) -------
__global__ __launch_bounds__(256) void kupdate(const float* __restrict__ feats,
                                               const float* __restrict__ x,
                                               const int* __restrict__ tgt,
                                               float* __restrict__ outF) {
  int b = blockIdx.x, t = threadIdx.x;
  int y = tgt[b];
  for (int i = 0; i < b; i++) if (tgt[i] == y) return;  // block-uniform exit
  float f[8];
  #pragma unroll
  for (int i = 0; i < 8; i++) f[i] = feats[(size_t)y * D_ + t + i * 256];
  for (int b2 = b; b2 < B_; b2++) {
    if (tgt[b2] != y) continue;  // block-uniform
    float ss = 0.f;
    #pragma unroll
    for (int i = 0; i < 8; i++) {
      f[i] = MOM * f[i] + (1.0f - MOM) * x[(size_t)b2 * D_ + t + i * 256];
      ss += f[i] * f[i];
    }
    float tot = blockReduceSum256(ss);
    float inv = 1.0f / (sqrtf(tot) + EPSF);
    #pragma unroll
    for (int i = 0; i < 8; i++) f[i] *= inv;
  }
  #pragma unroll
  for (int i = 0; i < 8; i++) outF[(size_t)y * D_ + t + i * 256] = f[i];
}

extern "C" void kernel_launch(void* const* d_in, const int* in_sizes, int n_in,
                              void* d_out, int out_size, void* d_ws, size_t ws_size,
                              hipStream_t stream) {
  const float* inputs = (const float*)d_in[0];
  const float* feats  = (const float*)d_in[1];
  const int*   tgt    = (const int*)d_in[2];
  float* out  = (float*)d_out;
  float* outF = out + 1;  // new_features, N_ x D_, 4-byte aligned only

  char* ws = (char*)d_ws;
  float*          x    = (float*)ws;                                   // 2 MB
  unsigned short* xbf  = (unsigned short*)(ws + (size_t)B_ * D_ * 4);  // 1 MB
  float*          pmax = (float*)(ws + (size_t)B_ * D_ * 4 + (size_t)B_ * D_ * 2);
  float*          psum = pmax + (size_t)B_ * NT;
  float*          tdot = psum + (size_t)B_ * NT;
  float*          lb   = tdot + B_;

  hipLaunchKernelGGL(knorm,   dim3(B_),  dim3(256), 0, stream, inputs, x, xbf);
  hipLaunchKernelGGL(kmain,   dim3(NT),  dim3(384), 0, stream, feats, xbf, out, pmax, psum);
  hipLaunchKernelGGL(ktdot,   dim3(B_),  dim3(256), 0, stream, feats, x, tgt, tdot);
  hipLaunchKernelGGL(kloss1,  dim3(B_),  dim3(256), 0, stream, pmax, psum, tdot, lb);
  hipLaunchKernelGGL(kloss2,  dim3(1),   dim3(256), 0, stream, lb, out);
  hipLaunchKernelGGL(kupdate, dim3(B_),  dim3(256), 0, stream, feats, x, tgt, outF);
}

// Round 5
// 272.705 us; speedup vs baseline: 1.6125x; 1.6125x over previous
//
#include <hip/hip_runtime.h>
#include <hip/hip_bf16.h>

#define B_ 256
#define D_ 2048
#define N_ 30000
#define INV_TEMP 20.0f
#define MOM 0.2f
#define EPSF 1e-12f
#define BN 16
#define KC 64
#define NT 1875  // 30000 / 16
#define NK 32    // D_ / KC

typedef __attribute__((ext_vector_type(8))) short bf16x8;
typedef __attribute__((ext_vector_type(4))) float f32x4;

typedef const __attribute__((address_space(1))) void* gas_t;
typedef __attribute__((address_space(3))) void* las_t;
#define GLOAD16(g, l) __builtin_amdgcn_global_load_lds((gas_t)(g), (las_t)(l), 16, 0, 0)

__device__ __forceinline__ unsigned short f2bf(float f) {
  union { float f; unsigned int u; } v; v.f = f;
  unsigned int u = v.u;
  unsigned int r = (u + 0x7fffu + ((u >> 16) & 1u)) >> 16;
  return (unsigned short)r;
}

__device__ __forceinline__ float blockReduceSum256(float v) {
  __shared__ float red[4];
  #pragma unroll
  for (int m = 32; m >= 1; m >>= 1) v += __shfl_xor(v, m, 64);
  int lane = threadIdx.x & 63, w = threadIdx.x >> 6;
  __syncthreads();
  if (lane == 0) red[w] = v;
  __syncthreads();
  return red[0] + red[1] + red[2] + red[3];
}

// ---------------- Kernel A: normalize inputs, emit fp32 + bf16 copies -------
__global__ __launch_bounds__(256) void knorm(const float* __restrict__ in,
                                             float* __restrict__ x,
                                             unsigned short* __restrict__ xbf) {
  int b = blockIdx.x, t = threadIdx.x;
  const float* row = in + (size_t)b * D_;
  float vals[8]; float ss = 0.f;
  #pragma unroll
  for (int i = 0; i < 8; i++) { float f = row[t + i * 256]; vals[i] = f; ss += f * f; }
  float tot = blockReduceSum256(ss);
  float inv = 1.0f / (sqrtf(tot) + EPSF);
  #pragma unroll
  for (int i = 0; i < 8; i++) {
    float xv = vals[i] * inv;
    x[(size_t)b * D_ + t + i * 256] = xv;
    xbf[(size_t)b * D_ + t + i * 256] = f2bf(xv);
  }
}

// ---------------- Kernel B: BN=16 tile GEMM + partials + fused bank copy ----
// 1875 blocks, 256 thr / 4 waves. Wave w owns batch rows [w*64, w*64+64),
// all 16 feature cols of the block. xs staged via global_load_lds (linear
// dest + inverse-swizzled global src); fs reg-staged with fused aligned
// float4 copy to out(+1).
__global__ __launch_bounds__(256, 4) void kmain(const float* __restrict__ feats,
                                                const unsigned short* __restrict__ xbf,
                                                float* __restrict__ outp,
                                                float* __restrict__ pmax,
                                                float* __restrict__ psum) {
  __shared__ __align__(16) unsigned short xs[16384];  // 256 rows x 64 cols bf16, 32 KB
  __shared__ __align__(16) unsigned short fs[1024];   // 16 rows x 64 cols bf16, 2 KB
  int tid = threadIdx.x, wave = tid >> 6, lane = tid & 63;
  int n0 = blockIdx.x * BN;
  int q = lane >> 4, lr = lane & 15;

  // gl_lds addressing: iter i stages rows i*32 + wave*8 + (l>>3), chunk l&7.
  int gswz = (lane & 7) ^ (lane >> 3);           // inverse-swizzled source chunk
  int rof = wave * 8 + (lane >> 3);
  const char* xsrc = (const char*)xbf;

  // fs staging / copy: thread -> row n=tid>>4 (block col), chunk c=tid&15
  int fn = tid >> 4, fcc = tid & 15;
  const float* fbase = feats + (size_t)(n0 + fn) * D_ + 4 * fcc;
  int sl = (lane & 48) | ((lane + 1) & 15);      // next chunk-thread in same row

  f32x4 acc[4];
  #pragma unroll
  for (int i = 0; i < 4; i++) acc[i] = f32x4{0.f, 0.f, 0.f, 0.f};

  for (int t = 0; t < NK; t++) {
    int k0 = t * KC;
    __syncthreads();   // previous compute done; xs/fs reusable; prior stores drain
    // ---- stage ----
    float4 fv = *(const float4*)(fbase + k0);
    size_t gb = ((size_t)rof * D_ + k0 + gswz * 8) * 2;
    #pragma unroll
    for (int i = 0; i < 8; i++)
      GLOAD16(xsrc + gb + (size_t)i * 32 * D_ * 2,
              (char*)xs + i * 4096 + wave * 1024);
    {
      ushort2 p0 = make_ushort2(f2bf(fv.x), f2bf(fv.y));
      ushort2 p1 = make_ushort2(f2bf(fv.z), f2bf(fv.w));
      int byte = fn * 128 + ((8 * fcc) ^ ((fn & 7) << 4));
      *(ushort2*)((char*)fs + byte) = p0;
      *(ushort2*)((char*)fs + byte + 4) = p1;
    }
    __syncthreads();   // drains vmcnt+lgkm: xs (gl_lds) and fs visible
    // ---- compute ----
    #pragma unroll
    for (int ks = 0; ks < 2; ks++) {
      int g = ks * 4 + q;
      bf16x8 a[4], bb;
      { int row = lr; bb = *(const bf16x8*)((char*)fs + row * 128 + ((g * 16) ^ ((row & 7) << 4))); }
      #pragma unroll
      for (int mi = 0; mi < 4; mi++) {
        int row = wave * 64 + mi * 16 + lr;
        a[mi] = *(const bf16x8*)((char*)xs + row * 128 + ((g * 16) ^ ((row & 7) << 4)));
      }
      #pragma unroll
      for (int mi = 0; mi < 4; mi++)
        acc[mi] = __builtin_amdgcn_mfma_f32_16x16x32_bf16(a[mi], bb, acc[mi], 0, 0, 0);
    }
    // ---- fused copy-out (after MFMA; stores drain at next top barrier) ----
    {
      float nx = __shfl(fv.x, sl, 64);
      float ny = __shfl(fv.y, sl, 64);
      float nz = __shfl(fv.z, sl, 64);
      size_t rb = (size_t)(n0 + fn) * D_ + k0;   // out-absolute base (+1 folded)
      if (fcc < 15)
        *(float4*)(outp + rb + 4 * fcc + 4) = make_float4(fv.w, nx, ny, nz);
      else
        outp[rb + 64] = fv.w;
      if (fcc == 0) { outp[rb + 1] = fv.x; outp[rb + 2] = fv.y; outp[rb + 3] = fv.z; }
    }
  }

  // ---- epilogue: per-row max/sumexp over this block's 16 cols (intra-wave) --
  #pragma unroll
  for (int mi = 0; mi < 4; mi++) {
    #pragma unroll
    for (int r = 0; r < 4; r++) {
      float v = acc[mi][r] * INV_TEMP;
      float mx = v;
      #pragma unroll
      for (int m = 8; m >= 1; m >>= 1) mx = fmaxf(mx, __shfl_xor(mx, m, 64));
      float s = __expf(v - mx);
      #pragma unroll
      for (int m = 8; m >= 1; m >>= 1) s += __shfl_xor(s, m, 64);
      if (lr == 0) {
        int row = wave * 64 + mi * 16 + q * 4 + r;
        pmax[(size_t)row * NT + blockIdx.x] = mx;
        psum[(size_t)row * NT + blockIdx.x] = s;
      }
    }
  }
}

// ---------------- Kernel C: exact fp32 target logits ------------------------
__global__ __launch_bounds__(256) void ktdot(const float* __restrict__ feats,
                                             const float* __restrict__ x,
                                             const int* __restrict__ tgt,
                                             float* __restrict__ tdot) {
  int b = blockIdx.x, t = threadIdx.x;
  int y = tgt[b];
  const float* fr = feats + (size_t)y * D_;
  const float* xr = x + (size_t)b * D_;
  float s = 0.f;
  #pragma unroll
  for (int i = 0; i < 8; i++) s += fr[t + i * 256] * xr[t + i * 256];
  float tot = blockReduceSum256(s);
  if (t == 0) tdot[b] = tot * INV_TEMP;
}

// ---------------- Kernel D1: per-row logsumexp combine (256 blocks) ---------
__global__ __launch_bounds__(256) void kloss1(const float* __restrict__ pmax,
                                              const float* __restrict__ psum,
                                              const float* __restrict__ tdot,
                                              float* __restrict__ lb) {
  int b = blockIdx.x, t = threadIdx.x;
  float m = -INFINITY, s = 0.f;
  for (int i = t; i < NT; i += 256) {
    float mt = pmax[(size_t)b * NT + i];
    float st = psum[(size_t)b * NT + i];
    if (mt > m) { s = s * __expf(m - mt) + st; m = mt; }
    else        { s += st * __expf(mt - m); }
  }
  #pragma unroll
  for (int w = 32; w >= 1; w >>= 1) {
    float mo = __shfl_xor(m, w, 64);
    float so = __shfl_xor(s, w, 64);
    float M = fmaxf(m, mo);
    s = s * __expf(m - M) + so * __expf(mo - M);
    m = M;
  }
  __shared__ float sm[4], ssum[4];
  int lane = t & 63, w = t >> 6;
  if (lane == 0) { sm[w] = m; ssum[w] = s; }
  __syncthreads();
  if (t == 0) {
    float M = fmaxf(fmaxf(sm[0], sm[1]), fmaxf(sm[2], sm[3]));
    float S = ssum[0] * __expf(sm[0] - M) + ssum[1] * __expf(sm[1] - M) +
              ssum[2] * __expf(sm[2] - M) + ssum[3] * __expf(sm[3] - M);
    lb[b] = M + logf(S) - tdot[b];
  }
}

// ---------------- Kernel D2: mean over batch -> loss ------------------------
__global__ __launch_bounds__(256) void kloss2(const float* __restrict__ lb,
                                              float* __restrict__ out) {
  int t = threadIdx.x;
  float tot = blockReduceSum256(lb[t]);
  if (t == 0) out[0] = tot * (1.0f / 256.0f);
}

// ---------------- Kernel E: momentum update (first-occurrence chains) -------
__global__ __launch_bounds__(256) void kupdate(const float* __restrict__ feats,
                                               const float* __restrict__ x,
                                               const int* __restrict__ tgt,
                                               float* __restrict__ outF) {
  int b = blockIdx.x, t = threadIdx.x;
  int y = tgt[b];
  for (int i = 0; i < b; i++) if (tgt[i] == y) return;  // block-uniform exit
  float f[8];
  #pragma unroll
  for (int i = 0; i < 8; i++) f[i] = feats[(size_t)y * D_ + t + i * 256];
  for (int b2 = b; b2 < B_; b2++) {
    if (tgt[b2] != y) continue;  // block-uniform
    float ss = 0.f;
    #pragma unroll
    for (int i = 0; i < 8; i++) {
      f[i] = MOM * f[i] + (1.0f - MOM) * x[(size_t)b2 * D_ + t + i * 256];
      ss += f[i] * f[i];
    }
    float tot = blockReduceSum256(ss);
    float inv = 1.0f / (sqrtf(tot) + EPSF);
    #pragma unroll
    for (int i = 0; i < 8; i++) f[i] *= inv;
  }
  #pragma unroll
  for (int i = 0; i < 8; i++) outF[(size_t)y * D_ + t + i * 256] = f[i];
}

extern "C" void kernel_launch(void* const* d_in, const int* in_sizes, int n_in,
                              void* d_out, int out_size, void* d_ws, size_t ws_size,
                              hipStream_t stream) {
  const float* inputs = (const float*)d_in[0];
  const float* feats  = (const float*)d_in[1];
  const int*   tgt    = (const int*)d_in[2];
  float* out  = (float*)d_out;
  float* outF = out + 1;  // new_features, N_ x D_, 4-byte aligned only

  char* ws = (char*)d_ws;
  float*          x    = (float*)ws;                                   // 2 MB
  unsigned short* xbf  = (unsigned short*)(ws + (size_t)B_ * D_ * 4);  // 1 MB
  float*          pmax = (float*)(ws + (size_t)B_ * D_ * 4 + (size_t)B_ * D_ * 2);
  float*          psum = pmax + (size_t)B_ * NT;
  float*          tdot = psum + (size_t)B_ * NT;
  float*          lb   = tdot + B_;

  hipLaunchKernelGGL(knorm,   dim3(B_),  dim3(256), 0, stream, inputs, x, xbf);
  hipLaunchKernelGGL(kmain,   dim3(NT),  dim3(256), 0, stream, feats, xbf, out, pmax, psum);
  hipLaunchKernelGGL(ktdot,   dim3(B_),  dim3(256), 0, stream, feats, x, tgt, tdot);
  hipLaunchKernelGGL(kloss1,  dim3(B_),  dim3(256), 0, stream, pmax, psum, tdot, lb);
  hipLaunchKernelGGL(kloss2,  dim3(1),   dim3(256), 0, stream, lb, out);
  hipLaunchKernelGGL(kupdate, dim3(B_),  dim3(256), 0, stream, feats, x, tgt, outF);
}